// Round 9
// baseline (6257.438 us; speedup 1.0000x reference)
//
#include <hip/hip_runtime.h>
#include <stdint.h>

// ---------------------------------------------------------------------------
// Model constants
// ---------------------------------------------------------------------------
#define BATCH       64
#define SEQ_LEN     2048
#define D_MODEL     128
#define WIN         64
#define NWIN        64
#define PRED_LEN    4
#define XSTRIDE     2052   // SEQ_LEN + PRED_LEN
#define NTH         512    // 8 waves: waves 0-3 -> elem 0, waves 4-7 -> elem 1
#define MAINB       32     // 32 blocks x 2 batch elements
#define WINB        128    // 128 blocks x 2 slots x 16 seq windows = 4096
#define WPB         16
#define XELEM       6912   // per-element xsh stride (floats); 2x = 55296 B LDS

typedef _Float16 h2 __attribute__((ext_vector_type(2)));

#define PIN(x)  asm volatile("" : "+v"(x))

__device__ __forceinline__ const float* launder(const float* p) {
    uintptr_t v = (uintptr_t)p; asm volatile("" : "+s"(v)); return (const float*)v;
}
__device__ __forceinline__ const _Float16* launder16(const _Float16* p) {
    uintptr_t v = (uintptr_t)p; asm volatile("" : "+s"(v)); return (const _Float16*)v;
}

// packed-f16 dot2: acc += a.x*b.x + a.y*b.y  (V_DOT2_F32_F16)
__device__ __forceinline__ float dot2f(float a, float b, float acc) {
#if __has_builtin(__builtin_amdgcn_fdot2)
    return __builtin_amdgcn_fdot2(__builtin_bit_cast(h2, a),
                                  __builtin_bit_cast(h2, b), acc, false);
#else
    h2 av = __builtin_bit_cast(h2, a), bv = __builtin_bit_cast(h2, b);
    return fmaf((float)av.x, (float)bv.x, fmaf((float)av.y, (float)bv.y, acc));
#endif
}

// ---------------------------------------------------------------------------
// Threefry-2x32 (exact jax implementation)
// ---------------------------------------------------------------------------
__device__ __forceinline__ uint32_t rotl32(uint32_t v, int d) {
    return (v << d) | (v >> (32 - d));
}
__device__ __forceinline__ void threefry2x32(uint32_t k0, uint32_t k1,
                                             uint32_t x0, uint32_t x1,
                                             uint32_t& o0, uint32_t& o1) {
    uint32_t ks0 = k0, ks1 = k1, ks2 = k0 ^ k1 ^ 0x1BD11BDAu;
    x0 += ks0; x1 += ks1;
#define TF_R(r) { x0 += x1; x1 = rotl32(x1, r); x1 ^= x0; }
    TF_R(13) TF_R(15) TF_R(26) TF_R(6)
    x0 += ks1; x1 += ks2 + 1u;
    TF_R(17) TF_R(29) TF_R(16) TF_R(24)
    x0 += ks2; x1 += ks0 + 2u;
    TF_R(13) TF_R(15) TF_R(26) TF_R(6)
    x0 += ks0; x1 += ks1 + 3u;
    TF_R(17) TF_R(29) TF_R(16) TF_R(24)
    x0 += ks1; x1 += ks2 + 4u;
    TF_R(13) TF_R(15) TF_R(26) TF_R(6)
    x0 += ks2; x1 += ks0 + 5u;
#undef TF_R
    o0 = x0; o1 = x1;
}

__device__ __forceinline__ float sigf(float x) { return 1.f / (1.f + __expf(-x)); }
__device__ __forceinline__ float tanhf_(float x) {
    float e = __expf(2.f * x);
    return 1.f - 2.f / (e + 1.f);
}

// ---------------------------------------------------------------------------
// init / convert
// ---------------------------------------------------------------------------
__global__ void init_kernel(const float* __restrict__ bx, float* __restrict__ xext) {
    int idx = blockIdx.x * 256 + threadIdx.x;
    if (idx < BATCH * SEQ_LEN) {
        int b = idx >> 11, t = idx & 2047;
        xext[(size_t)b * XSTRIDE + t] = bx[idx];
    }
}

__global__ void convert_kernel(const float* __restrict__ Wg, const float* __restrict__ Ww,
                               _Float16* __restrict__ g16, _Float16* __restrict__ w16) {
    int idx = blockIdx.x * 256 + threadIdx.x;
    if (idx < 384 * 128) {
        g16[idx] = (_Float16)Wg[idx];
        w16[idx] = (_Float16)Ww[idx];
    }
}

// ---------------------------------------------------------------------------
// prep: per-batch mean/std (fp64, ddof=1), threefry starts, Q gather
// ---------------------------------------------------------------------------
__global__ void prep_kernel(const float* __restrict__ xext,
                            int* __restrict__ starts, float* __restrict__ Q,
                            int T, int stepIdx) {
    int b = blockIdx.x, tid = threadIdx.x;
    const float* xb = xext + (size_t)b * XSTRIDE;

    double s = 0.0, s2 = 0.0;
    for (int t = tid; t < T; t += 256) { double v = (double)xb[t]; s += v; s2 += v * v; }
    __shared__ double rs[256], rs2[256];
    rs[tid] = s; rs2[tid] = s2;
    __syncthreads();
    for (int off = 128; off > 0; off >>= 1) {
        if (tid < off) { rs[tid] += rs[tid + off]; rs2[tid] += rs2[tid + off]; }
        __syncthreads();
    }
    __shared__ float thr_s;
    if (tid == 0) {
        double mean = rs[0] / (double)T;
        double var = (rs2[0] - (double)T * mean * mean) / (double)(T - 1);
        if (var < 0.0) var = 0.0;
        thr_s = (float)(mean + 1.48 * sqrt(var));
    }
    __syncthreads();

    if (tid < NWIN) {
        uint32_t ka, kb;
        threefry2x32(0u, 42u, 0u, (uint32_t)stepIdx, ka, kb);
        uint32_t A0, B0, A1, B1;
        threefry2x32(ka, kb, 0u, 2u, A0, B0);
        threefry2x32(ka, kb, 1u, 3u, A1, B1);

        uint32_t idx = (uint32_t)(b * NWIN + tid);
        uint32_t q = idx & 2047u;
        uint32_t h0, h1, l0, l1;
        threefry2x32(A0, A1, q, q + 2048u, h0, h1);
        threefry2x32(B0, B1, q, q + 2048u, l0, l1);
        uint32_t hi = (idx < 2048u) ? h0 : h1;
        uint32_t lo = (idx < 2048u) ? l0 : l1;

        uint32_t span = (uint32_t)(T - WIN);
        uint32_t mult = 65536u % span;
        mult = (mult * mult) % span;
        uint32_t off = ((hi % span) * mult + (lo % span)) % span;
        starts[idx] = (int)off;
        Q[idx] = (xb[off + WIN] > thr_s) ? 1.f : 0.f;
    }
}

// ---------------------------------------------------------------------------
// FUSED GRU (f16-dot2 VALU), 2 independent elements per block.
// Block = 2 batch elements (main, blocks 0..31) or 2 window slots x 16
// sequential windows (blocks 32..159).  512 threads: elem = tid>>8 (waves
// 0-3 / 4-7), r = tid&255, tid-in-elem = j*2 + kh.  Each SIMD carries TWO
// independent recurrence chains (one per element) that interleave to hide
// the per-step latency chain (ds_read ~120cyc + dot chain + trans) that
// left round-8's single-chain tail at 43% VALUBusy.  Thread holds Wh rows
// (j, j+128, j+256), k-half kh as 96 packed-f16 pairs register-resident.
// h ping-pongs through LDS f16[128] per element; wave-level reads are
// 2-address broadcasts (free).  One xor-1 shuffle (DPP) completes the dot.
// ---------------------------------------------------------------------------
#define GSTEP(CUR, XV)                                                       \
    do {                                                                     \
        float xv_ = (XV);                                                    \
        float ar = 0.f, az = 0.f, an = 0.f;                                  \
        const float4* hp_ = (CUR) ? h1base : h0base;                         \
        _Pragma("unroll")                                                    \
        for (int c = 0; c < 8; ++c) {                                        \
            float4 hv = hp_[c];                                              \
            ar = dot2f(hv.x, wpk[0][4*c+0], ar);                             \
            ar = dot2f(hv.y, wpk[0][4*c+1], ar);                             \
            ar = dot2f(hv.z, wpk[0][4*c+2], ar);                             \
            ar = dot2f(hv.w, wpk[0][4*c+3], ar);                             \
            az = dot2f(hv.x, wpk[1][4*c+0], az);                             \
            az = dot2f(hv.y, wpk[1][4*c+1], az);                             \
            az = dot2f(hv.z, wpk[1][4*c+2], az);                             \
            az = dot2f(hv.w, wpk[1][4*c+3], az);                             \
            an = dot2f(hv.x, wpk[2][4*c+0], an);                             \
            an = dot2f(hv.y, wpk[2][4*c+1], an);                             \
            an = dot2f(hv.z, wpk[2][4*c+2], an);                             \
            an = dot2f(hv.w, wpk[2][4*c+3], an);                             \
        }                                                                    \
        ar += __shfl_xor(ar, 1);                                             \
        az += __shfl_xor(az, 1);                                             \
        an += __shfl_xor(an, 1);                                             \
        float r = sigf(fmaf(xv_, wir, br) + ar);                             \
        float z = sigf(fmaf(xv_, wiz, bz) + az);                             \
        float n = tanhf_(fmaf(xv_, win, bin) + r * (an + bhn));              \
        hold = fmaf(z, hold - n, n);                                         \
        if (kh == 0) *((CUR) ? hw0 : hw1) = (_Float16)hold;                  \
        __syncthreads();                                                     \
    } while (0)

__global__
__attribute__((amdgpu_flat_work_group_size(NTH, NTH), amdgpu_waves_per_eu(2, 2)))
void gru_fused_kernel(const float* __restrict__ xext, float* __restrict__ hstate,
                      const int* __restrict__ starts, float* __restrict__ S,
                      const _Float16* wh16g, const float* Wi_g_,
                      const float* bi_g_, const float* bh_g_,
                      const _Float16* wh16w, const float* Wi_w_,
                      const float* bi_w_, const float* bh_w_,
                      int L, int initFlag) {
    __shared__ float xsh[2 * XELEM];                    // per-elem x staging
    __shared__ __align__(16) _Float16 hsh[2][2][D_MODEL]; // [elem][buf][j]

    const int tid  = threadIdx.x;
    const int elem = tid >> 8;        // wave-uniform (waves 0-3 / 4-7)
    const int r_l  = tid & 255;
    const int j  = r_l >> 1;
    const int kh = r_l & 1;
    const bool isMain = (blockIdx.x < MAINB);

    const _Float16* wh16 = launder16(isMain ? wh16g : wh16w);
    const float* Wi = launder(isMain ? Wi_g_ : Wi_w_);
    const float* bi = launder(isMain ? bi_g_ : bi_w_);
    const float* bh = launder(isMain ? bh_g_ : bh_w_);

    // ---- weights: 3 gates x 32 packed-f16 pairs, register-resident ----
    float wpk[3][32];
#pragma unroll
    for (int g = 0; g < 3; ++g) {
        const float4* wp = (const float4*)(wh16 + (size_t)(g * 128 + j) * 128 + kh * 64);
#pragma unroll
        for (int c = 0; c < 8; ++c) {
            float4 v = wp[c];
            wpk[g][4*c+0] = v.x; wpk[g][4*c+1] = v.y;
            wpk[g][4*c+2] = v.z; wpk[g][4*c+3] = v.w;
        }
    }
#pragma unroll
    for (int g = 0; g < 3; ++g)
#pragma unroll
        for (int p = 0; p < 32; ++p) PIN(wpk[g][p]);

    float wir = Wi[j], wiz = Wi[j + 128], win = Wi[j + 256];
    float br  = bi[j] + bh[j];
    float bz  = bi[j + 128] + bh[j + 128];
    float bin = bi[j + 256], bhn = bh[j + 256];
    PIN(wir); PIN(wiz); PIN(win); PIN(br); PIN(bz); PIN(bin); PIN(bhn);

    float* xe = &xsh[elem * XELEM];
    const float4* h0base = (const float4*)&hsh[elem][0][kh * 64];
    const float4* h1base = (const float4*)&hsh[elem][1][kh * 64];
    _Float16* hw0 = &hsh[elem][0][j];   // written by odd steps  (read buf1)
    _Float16* hw1 = &hsh[elem][1][j];   // written by even steps (read buf0)

    float hold;

    if (isMain) {
        const int b = blockIdx.x * 2 + elem;
        for (int t = r_l; t < L; t += 256)
            xe[t] = xext[(size_t)b * XSTRIDE + t];
        hold = initFlag ? 0.f : hstate[b * D_MODEL + j];
        if (kh == 0) hsh[elem][0][j] = (_Float16)hold;
        __syncthreads();

        int t = 0;
        for (; t + 1 < L; t += 2) {
            GSTEP(0, xe[t]);
            GSTEP(1, xe[t + 1]);
        }
        if (t < L) GSTEP(0, xe[t]);
        if (kh == 0) hstate[b * D_MODEL + j] = hold;
    } else {
        const int slot = (blockIdx.x - MAINB) * 2 + elem;   // 0..255
        for (int w = 0; w < WPB; ++w) {
            int widx = slot * WPB + w;
            int b = widx >> 6;
            int st = starts[widx];
            if (r_l < WIN) xe[r_l] = xext[(size_t)b * XSTRIDE + st + r_l];
            if (kh == 0) hsh[elem][0][j] = (_Float16)0.f;
            hold = 0.f;
            __syncthreads();

#pragma unroll 1
            for (int s = 0; s < WIN; s += 2) {
                GSTEP(0, xe[s]);
                GSTEP(1, xe[s + 1]);
            }
            if (kh == 0) S[(size_t)widx * D_MODEL + j] = hold;
            __syncthreads();   // before next window rewrites xe/hsh
        }
    }
}

// ---------------------------------------------------------------------------
// finalize: attention + output.  One wave per batch element.
// ---------------------------------------------------------------------------
__global__ void finalize_kernel(float* __restrict__ xext,
                                const float* __restrict__ hstate,
                                const float* __restrict__ S,
                                const float* __restrict__ Q,
                                const float* __restrict__ Wd, const float* __restrict__ bd,
                                const float* __restrict__ Wc, const float* __restrict__ bc,
                                float* __restrict__ out, int stepIdx) {
    int b = blockIdx.x;
    int m = threadIdx.x;  // 64 threads = 1 wave

    __shared__ float Hs[D_MODEL];
    Hs[m]      = hstate[b * D_MODEL + m];
    Hs[m + 64] = hstate[b * D_MODEL + 64 + m];
    __syncthreads();

    const float* Srow = S + (size_t)(b * NWIN + m) * D_MODEL;
    float acc = 0.f;
#pragma unroll
    for (int jj = 0; jj < D_MODEL; ++jj)
        acc = fmaf(Hs[jj], Srow[jj], acc);

    float mx = acc;
#pragma unroll
    for (int d = 1; d < 64; d <<= 1) mx = fmaxf(mx, __shfl_xor(mx, d));
    float e = __expf(acc - mx);
    float se = e;
#pragma unroll
    for (int d = 1; d < 64; d <<= 1) se += __shfl_xor(se, d);
    float A = e / se;

    float qa = Q[b * NWIN + m] * A;
#pragma unroll
    for (int d = 1; d < 64; d <<= 1) qa += __shfl_xor(qa, d);

    float po = Hs[m] * Wd[m] + Hs[m + 64] * Wd[m + 64];
#pragma unroll
    for (int d = 1; d < 64; d <<= 1) po += __shfl_xor(po, d);

    if (m == 0) {
        float o = po + bd[0];
        float u = sigf(fmaf(qa, Wc[0], bc[0]));
        float y = o + u;
        xext[(size_t)b * XSTRIDE + SEQ_LEN + stepIdx] = y;
        out[b * PRED_LEN + stepIdx] = y;
        out[BATCH * PRED_LEN + b * PRED_LEN + stepIdx] = u;
    }
}

// ---------------------------------------------------------------------------
// kernel_launch
// ---------------------------------------------------------------------------
extern "C" void kernel_launch(void* const* d_in, const int* in_sizes, int n_in,
                              void* d_out, int out_size, void* d_ws, size_t ws_size,
                              hipStream_t stream) {
    const float* batch_x = (const float*)d_in[0];
    const float* Wi_g = (const float*)d_in[4];
    const float* Wh_g = (const float*)d_in[5];
    const float* bi_g = (const float*)d_in[6];
    const float* bh_g = (const float*)d_in[7];
    const float* Wi_w = (const float*)d_in[8];
    const float* Wh_w = (const float*)d_in[9];
    const float* bi_w = (const float*)d_in[10];
    const float* bh_w = (const float*)d_in[11];
    const float* Wd   = (const float*)d_in[12];
    const float* bd   = (const float*)d_in[13];
    const float* Wc   = (const float*)d_in[16];
    const float* bc   = (const float*)d_in[17];
    float* out = (float*)d_out;

    // workspace layout
    float* ws = (float*)d_ws;
    float* xext   = ws;                                   // 131328 f
    float* hstate = xext + BATCH * XSTRIDE;               // 8192 f
    float* Q      = hstate + BATCH * D_MODEL;             // 4096 f
    float* Sbuf   = Q + BATCH * NWIN;                     // 524288 f
    int*   starts = (int*)(Sbuf + (size_t)BATCH * NWIN * D_MODEL); // 4096 i
    _Float16* wh16g = (_Float16*)(starts + BATCH * NWIN); // 49152 h
    _Float16* wh16w = wh16g + 384 * 128;                  // 49152 h

    init_kernel<<<512, 256, 0, stream>>>(batch_x, xext);
    convert_kernel<<<192, 256, 0, stream>>>(Wh_g, Wh_w, wh16g, wh16w);

    for (int i = 0; i < PRED_LEN; ++i) {
        int T = SEQ_LEN + i;
        int L = (i == 0) ? SEQ_LEN : (SEQ_LEN - 1 + i);

        prep_kernel<<<BATCH, 256, 0, stream>>>(xext, starts, Q, T, i);
        gru_fused_kernel<<<MAINB + WINB, NTH, 0, stream>>>(
            xext, hstate, starts, Sbuf,
            wh16g, Wi_g, bi_g, bh_g,
            wh16w, Wi_w, bi_w, bh_w,
            L, (i == 0) ? 1 : 0);
        finalize_kernel<<<BATCH, 64, 0, stream>>>(xext, hstate, Sbuf, Q,
                                                  Wd, bd, Wc, bc, out, i);
    }
}